// Round 5
// baseline (470.723 us; speedup 1.0000x reference)
//
#include <hip/hip_runtime.h>
#include <hip/hip_bf16.h>
#include <hip/hip_cooperative_groups.h>

namespace cg = cooperative_groups;

typedef __attribute__((ext_vector_type(4))) float f32x4;

// ---------------- unified workspace layout (fp32 elements) ----------------
constexpr int WSF_GH   = 0;        // 6144   Whh*h + bhh, all layers (R = l*1536 + g*512 + u)
constexpr int WSF_Q    = 6144;     // 512    attention query (conv3 out)
constexpr int WSF_DEN  = 6656;     // 512    fused per-block exp-sum partials
constexpr int WSF_LOGA = 7168;     // 2048   (fallback) attention logits
constexpr int WSF_ATTM = 9216;     // 128    (fallback)
constexpr int WSF_ATTS = 9344;     // 128    (fallback)
constexpr int WSF_PARTF= 9472;     // 32*1024 (fallback PV partials)
constexpr int WSF_PART = 65536;    // 512*1024 fused PV partials
constexpr int WSF_APP  = 589824;   // 1024   attention output (2*512)
constexpr int WSF_XT   = 590848;   // 5*512  xt chain
constexpr int WSF_LOGV = 593408;   // 50257  vocab logits
constexpr int WSF_PM   = 643840;   // 786
constexpr int WSF_PS   = 644864;   // 786
constexpr int NVOCAB   = 50257;
constexpr int NBLK_V   = 786;

__device__ __forceinline__ float wave_rsum(float v) {
#pragma unroll
    for (int o = 32; o > 0; o >>= 1) v += __shfl_down(v, o);
    return v; // lane 0 holds sum
}
__device__ __forceinline__ float sigm(float x) { return 1.0f / (1.0f + __expf(-x)); }

struct KParams {
    const float *emb;
    const float *c1w,*c1b,*c2w,*c2b,*c3w,*c3b,*c4w,*c4b,*c5w,*c5b,*c6w,*c6b;
    const float *g1,*bb1,*g2,*bb2,*g3,*bb3,*g4,*bb4,*g5,*bb5,*g6,*bb6;
    const float *attw,*attb,*wih,*whh,*bih,*bhh,*hstate,*enc;
    const int *x;
    float *ws;
    float *out;
};

// =====================================================================
// FUSED HEAD (cooperative): gruh||pre-conv -> attention -> reduce ->
// post-conv -> 4x GRU.  512 blocks x 256 threads, ~78.5 KB LDS (2/CU).
// =====================================================================
__global__ __launch_bounds__(256) void k_head(KParams P)
{
    // LDS: single arena
    constexpr int OW = 0;        // conv weights (1089)
    constexpr int OSTAT = 1092;  // 64
    constexpr int OPRE = 1160;   // 5*512
    constexpr int OY = 3720;     // 32*512 (also generic scratch SCR)
    __shared__ float sm[20104];

    const int tid = threadIdx.x, lane = tid & 63, wid = tid >> 6;
    const int bid = blockIdx.x;
    float* ws = P.ws;
    cg::grid_group grid = cg::this_grid();

    // ---------------- P0: gruh (all blocks) + pre-conv (block 0) ----------------
#pragma unroll 1
    for (int t = 0; t < 3; ++t) {
        const int R = bid * 12 + wid * 3 + t;             // 0..6143
        const int l = R / 1536;
        const float* hp = P.hstate + l * 512;
        const float* wr = P.whh + (size_t)R * 512;
        f32x4 w0 = *(const f32x4*)(wr + lane * 4);
        f32x4 w1 = *(const f32x4*)(wr + 256 + lane * 4);
        f32x4 h0 = *(const f32x4*)(hp + lane * 4);
        f32x4 h1 = *(const f32x4*)(hp + 256 + lane * 4);
        float a = 0.f;
#pragma unroll
        for (int j = 0; j < 4; ++j) a += w0[j] * h0[j] + w1[j] * h1[j];
        a = wave_rsum(a);
        if (lane == 0) ws[WSF_GH + R] = a + P.bhh[R];
    }
    if (bid == 0) {
        // stage params
        for (int i = tid; i < 480; i += 256) { sm[OW + i] = P.c1w[i]; sm[OW + 576 + i] = P.c2w[i]; }
        if (tid < 32) { sm[OW+480+tid] = P.c1b[tid]; sm[OW+512+tid] = P.g1[tid]; sm[OW+544+tid] = P.bb1[tid]; }
        if (tid < 5)  { sm[OW+1056+tid] = P.c2b[tid]; sm[OW+1061+tid] = P.g2[tid]; sm[OW+1066+tid] = P.bb2[tid]; }
        if (tid < 15) sm[OW+1071+tid] = P.c3w[tid];
        if (tid == 0) { sm[OW+1086] = P.c3b[0]; sm[OW+1087] = P.g3[0]; sm[OW+1088] = P.bb3[0]; }
        const int x = P.x[0];
#pragma unroll
        for (int c = 0; c < 4; ++c) {
            sm[OPRE + c*512 + tid]       = P.hstate[c*512 + tid];
            sm[OPRE + c*512 + 256 + tid] = P.hstate[c*512 + 256 + tid];
        }
        sm[OPRE + 4*512 + tid]       = P.emb[(size_t)x*512 + tid];
        sm[OPRE + 4*512 + 256 + tid] = P.emb[(size_t)x*512 + 256 + tid];
        __syncthreads();

        // conv1 (5->32), pre-BN into OY
#pragma unroll
        for (int pp = 0; pp < 2; ++pp) {
            const int l = tid + pp * 256;
            float px[5][3];
#pragma unroll
            for (int ic = 0; ic < 5; ++ic) {
                px[ic][0] = (l > 0)   ? sm[OPRE + ic*512 + l - 1] : 0.f;
                px[ic][1] =             sm[OPRE + ic*512 + l];
                px[ic][2] = (l < 511) ? sm[OPRE + ic*512 + l + 1] : 0.f;
            }
#pragma unroll 4
            for (int oc = 0; oc < 32; ++oc) {
                float a = sm[OW + 480 + oc];
#pragma unroll
                for (int ic = 0; ic < 5; ++ic)
#pragma unroll
                    for (int k = 0; k < 3; ++k)
                        a += sm[OW + oc*15 + ic*3 + k] * px[ic][k];
                sm[OY + oc*512 + l] = a;
            }
        }
        __syncthreads();
        // BN1 stats: wave handles 8 channels
#pragma unroll
        for (int t = 0; t < 8; ++t) {
            const int oc = wid * 8 + t;
            float s = 0.f, s2 = 0.f;
#pragma unroll
            for (int j = 0; j < 8; ++j) { float v = sm[OY + oc*512 + lane + j*64]; s += v; s2 += v*v; }
            s = wave_rsum(s); s2 = wave_rsum(s2);
            if (lane == 0) {
                float m = s * (1.f/512.f), var = s2 * (1.f/512.f) - m*m;
                sm[OSTAT + oc*2] = m; sm[OSTAT + oc*2 + 1] = rsqrtf(var + 1e-5f);
            }
        }
        __syncthreads();
#pragma unroll
        for (int pp = 0; pp < 2; ++pp) {
            const int l = tid + pp * 256;
#pragma unroll 4
            for (int oc = 0; oc < 32; ++oc) {
                float m = sm[OSTAT + oc*2], r = sm[OSTAT + oc*2 + 1];
                sm[OY + oc*512 + l] = fmaxf((sm[OY + oc*512 + l] - m) * r * sm[OW+512+oc] + sm[OW+544+oc], 0.f);
            }
        }
        __syncthreads();
        // conv2 (32->5) + residual
        float y2[2][5];
#pragma unroll
        for (int pp = 0; pp < 2; ++pp)
#pragma unroll
            for (int oc = 0; oc < 5; ++oc) y2[pp][oc] = sm[OW + 1056 + oc];
#pragma unroll 2
        for (int ic = 0; ic < 32; ++ic) {
#pragma unroll
            for (int pp = 0; pp < 2; ++pp) {
                const int l = tid + pp * 256;
                float c0 = (l > 0)   ? sm[OY + ic*512 + l - 1] : 0.f;
                float c1 =             sm[OY + ic*512 + l];
                float c2 = (l < 511) ? sm[OY + ic*512 + l + 1] : 0.f;
#pragma unroll
                for (int oc = 0; oc < 5; ++oc) {
                    const int base = OW + 576 + (oc*32 + ic)*3;
                    y2[pp][oc] += sm[base]*c0 + sm[base+1]*c1 + sm[base+2]*c2;
                }
            }
        }
#pragma unroll
        for (int pp = 0; pp < 2; ++pp) {
            const int l = tid + pp * 256;
#pragma unroll
            for (int oc = 0; oc < 5; ++oc) y2[pp][oc] += sm[OPRE + oc*512 + l];
        }
        __syncthreads();
#pragma unroll
        for (int pp = 0; pp < 2; ++pp) {
            const int l = tid + pp * 256;
#pragma unroll
            for (int oc = 0; oc < 5; ++oc) sm[OY + oc*512 + l] = y2[pp][oc];
        }
        __syncthreads();
#pragma unroll
        for (int t = 0; t < 2; ++t) {
            const int oc = wid + 4 * t;
            if (oc < 5) {
                float s = 0.f, s2 = 0.f;
#pragma unroll
                for (int j = 0; j < 8; ++j) { float v = sm[OY + oc*512 + lane + j*64]; s += v; s2 += v*v; }
                s = wave_rsum(s); s2 = wave_rsum(s2);
                if (lane == 0) {
                    float m = s * (1.f/512.f), var = s2 * (1.f/512.f) - m*m;
                    sm[OSTAT + oc*2] = m; sm[OSTAT + oc*2 + 1] = rsqrtf(var + 1e-5f);
                }
            }
        }
        __syncthreads();
#pragma unroll
        for (int pp = 0; pp < 2; ++pp) {
            const int l = tid + pp * 256;
#pragma unroll
            for (int oc = 0; oc < 5; ++oc) {
                float m = sm[OSTAT + oc*2], r = sm[OSTAT + oc*2 + 1];
                sm[OPRE + oc*512 + l] = fmaxf((y2[pp][oc] - m) * r * sm[OW+1061+oc] + sm[OW+1066+oc], 0.f);
            }
        }
        __syncthreads();
        // conv3 (5->1)
        float a3[2];
#pragma unroll
        for (int pp = 0; pp < 2; ++pp) {
            const int l = tid + pp * 256;
            float a = sm[OW + 1086];
#pragma unroll
            for (int ic = 0; ic < 5; ++ic) {
                float c0 = (l > 0)   ? sm[OPRE + ic*512 + l - 1] : 0.f;
                float c1 =             sm[OPRE + ic*512 + l];
                float c2 = (l < 511) ? sm[OPRE + ic*512 + l + 1] : 0.f;
                a += sm[OW+1071+ic*3]*c0 + sm[OW+1071+ic*3+1]*c1 + sm[OW+1071+ic*3+2]*c2;
            }
            a3[pp] = a;
            sm[OY + l] = a;
        }
        __syncthreads();
        if (wid == 0) {
            float s = 0.f, s2 = 0.f;
#pragma unroll
            for (int j = 0; j < 8; ++j) { float v = sm[OY + lane + j*64]; s += v; s2 += v*v; }
            s = wave_rsum(s); s2 = wave_rsum(s2);
            if (lane == 0) {
                float m = s * (1.f/512.f), var = s2 * (1.f/512.f) - m*m;
                sm[OSTAT] = m; sm[OSTAT+1] = rsqrtf(var + 1e-5f);
            }
        }
        __syncthreads();
#pragma unroll
        for (int pp = 0; pp < 2; ++pp) {
            const int l = tid + pp * 256;
            ws[WSF_Q + l] = fmaxf((a3[pp] - sm[OSTAT]) * sm[OSTAT+1] * sm[OW+1087] + sm[OW+1088], 0.f);
        }
    }
    grid.sync();

    // ---------------- P1: attention (fused logit+exp+PV partial), all blocks ----------------
    {
        const int row = bid * 4 + wid;
        float q0[4], q1[4];
#pragma unroll
        for (int j = 0; j < 4; ++j) {
            q0[j] = ws[WSF_Q + lane*4 + j];
            q1[j] = ws[WSF_Q + 256 + lane*4 + j];
        }
        const float* wr = P.attw + (size_t)row * 512;
        f32x4 w0 = *(const f32x4*)(wr + lane*4);
        f32x4 w1 = *(const f32x4*)(wr + 256 + lane*4);
        float a = 0.f;
#pragma unroll
        for (int j = 0; j < 4; ++j) a += w0[j]*q0[j] + w1[j]*q1[j];
        a = wave_rsum(a);
        if (lane == 0) sm[OY + wid] = __expf(a + P.attb[row]);   // |logit| << 80: exp safe, == softmax
        __syncthreads();
        const float e0 = sm[OY+0], e1 = sm[OY+1], e2 = sm[OY+2], e3 = sm[OY+3];
        const int col = tid * 4;
        const float* ep = P.enc + (size_t)(bid*4) * 1024 + col;
        f32x4 v0 = *(const f32x4*)(ep);
        f32x4 v1 = *(const f32x4*)(ep + 1024);
        f32x4 v2 = *(const f32x4*)(ep + 2048);
        f32x4 v3 = *(const f32x4*)(ep + 3072);
        f32x4 acc = e0*v0 + e1*v1 + e2*v2 + e3*v3;
        *(f32x4*)(ws + WSF_PART + (size_t)bid*1024 + col) = acc;
        if (tid == 0) ws[WSF_DEN + bid] = e0 + e1 + e2 + e3;
    }
    grid.sync();

    // ---------------- P2: reduce partials -> app (blocks 0..15) ----------------
    if (bid < 16) {
        float d = ws[WSF_DEN + tid] + ws[WSF_DEN + 256 + tid];
        sm[OY + tid] = d;
        __syncthreads();
        for (int st = 128; st > 0; st >>= 1) {
            if (tid < st) sm[OY + tid] += sm[OY + tid + st];
            __syncthreads();
        }
        const float den = sm[OY];
        __syncthreads();
        const int col = bid * 64 + lane;
        float s = 0.f;
#pragma unroll 8
        for (int p = wid * 128; p < wid * 128 + 128; ++p)
            s += ws[WSF_PART + (size_t)p * 1024 + col];
        sm[OY + wid * 64 + lane] = s;
        __syncthreads();
        if (wid == 0) {
            float t4 = sm[OY+lane] + sm[OY+64+lane] + sm[OY+128+lane] + sm[OY+192+lane];
            ws[WSF_APP + col] = t4 / den;
        }
    }
    grid.sync();

    // ---------------- P3: post conv stack (block 0) ----------------
    if (bid == 0) {
        for (int i = tid; i < 288; i += 256) { sm[OW + i] = P.c4w[i]; sm[OW + 384 + i] = P.c5w[i]; }
        if (tid < 32) { sm[OW+288+tid] = P.c4b[tid]; sm[OW+320+tid] = P.g4[tid]; sm[OW+352+tid] = P.bb4[tid]; }
        if (tid < 3)  { sm[OW+672+tid] = P.c5b[tid]; sm[OW+675+tid] = P.g5[tid]; sm[OW+678+tid] = P.bb5[tid]; }
        if (tid < 9)  sm[OW+681+tid] = P.c6w[tid];
        if (tid == 0) { sm[OW+690] = P.c6b[0]; sm[OW+691] = P.g6[0]; sm[OW+692] = P.bb6[0]; }
        const int x = P.x[0];
#pragma unroll
        for (int pp = 0; pp < 2; ++pp) {
            const int l = tid + pp * 256;
            sm[OPRE + 0*512 + l] = ws[WSF_APP + l];
            sm[OPRE + 1*512 + l] = ws[WSF_APP + 512 + l];
            sm[OPRE + 2*512 + l] = P.emb[(size_t)x*512 + l];
        }
        __syncthreads();

        // conv4 (3->32)
#pragma unroll
        for (int pp = 0; pp < 2; ++pp) {
            const int l = tid + pp * 256;
            float px[3][3];
#pragma unroll
            for (int ic = 0; ic < 3; ++ic) {
                px[ic][0] = (l > 0)   ? sm[OPRE + ic*512 + l - 1] : 0.f;
                px[ic][1] =             sm[OPRE + ic*512 + l];
                px[ic][2] = (l < 511) ? sm[OPRE + ic*512 + l + 1] : 0.f;
            }
#pragma unroll 4
            for (int oc = 0; oc < 32; ++oc) {
                float a = sm[OW + 288 + oc];
#pragma unroll
                for (int ic = 0; ic < 3; ++ic)
#pragma unroll
                    for (int k = 0; k < 3; ++k)
                        a += sm[OW + oc*9 + ic*3 + k] * px[ic][k];
                sm[OY + oc*512 + l] = a;
            }
        }
        __syncthreads();
#pragma unroll
        for (int t = 0; t < 8; ++t) {
            const int oc = wid * 8 + t;
            float s = 0.f, s2 = 0.f;
#pragma unroll
            for (int j = 0; j < 8; ++j) { float v = sm[OY + oc*512 + lane + j*64]; s += v; s2 += v*v; }
            s = wave_rsum(s); s2 = wave_rsum(s2);
            if (lane == 0) {
                float m = s * (1.f/512.f), var = s2 * (1.f/512.f) - m*m;
                sm[OSTAT + oc*2] = m; sm[OSTAT + oc*2 + 1] = rsqrtf(var + 1e-5f);
            }
        }
        __syncthreads();
#pragma unroll
        for (int pp = 0; pp < 2; ++pp) {
            const int l = tid + pp * 256;
#pragma unroll 4
            for (int oc = 0; oc < 32; ++oc) {
                float m = sm[OSTAT + oc*2], r = sm[OSTAT + oc*2 + 1];
                sm[OY + oc*512 + l] = fmaxf((sm[OY + oc*512 + l] - m) * r * sm[OW+320+oc] + sm[OW+352+oc], 0.f);
            }
        }
        __syncthreads();
        // conv5 (32->3) + residual
        float y2[2][3];
#pragma unroll
        for (int pp = 0; pp < 2; ++pp)
#pragma unroll
            for (int oc = 0; oc < 3; ++oc) y2[pp][oc] = sm[OW + 672 + oc];
#pragma unroll 2
        for (int ic = 0; ic < 32; ++ic) {
#pragma unroll
            for (int pp = 0; pp < 2; ++pp) {
                const int l = tid + pp * 256;
                float c0 = (l > 0)   ? sm[OY + ic*512 + l - 1] : 0.f;
                float c1 =             sm[OY + ic*512 + l];
                float c2 = (l < 511) ? sm[OY + ic*512 + l + 1] : 0.f;
#pragma unroll
                for (int oc = 0; oc < 3; ++oc) {
                    const int base = OW + 384 + (oc*32 + ic)*3;
                    y2[pp][oc] += sm[base]*c0 + sm[base+1]*c1 + sm[base+2]*c2;
                }
            }
        }
#pragma unroll
        for (int pp = 0; pp < 2; ++pp) {
            const int l = tid + pp * 256;
#pragma unroll
            for (int oc = 0; oc < 3; ++oc) y2[pp][oc] += sm[OPRE + oc*512 + l];
        }
        __syncthreads();
#pragma unroll
        for (int pp = 0; pp < 2; ++pp) {
            const int l = tid + pp * 256;
#pragma unroll
            for (int oc = 0; oc < 3; ++oc) sm[OY + oc*512 + l] = y2[pp][oc];
        }
        __syncthreads();
        if (wid < 3) {
            const int oc = wid;
            float s = 0.f, s2 = 0.f;
#pragma unroll
            for (int j = 0; j < 8; ++j) { float v = sm[OY + oc*512 + lane + j*64]; s += v; s2 += v*v; }
            s = wave_rsum(s); s2 = wave_rsum(s2);
            if (lane == 0) {
                float m = s * (1.f/512.f), var = s2 * (1.f/512.f) - m*m;
                sm[OSTAT + oc*2] = m; sm[OSTAT + oc*2 + 1] = rsqrtf(var + 1e-5f);
            }
        }
        __syncthreads();
#pragma unroll
        for (int pp = 0; pp < 2; ++pp) {
            const int l = tid + pp * 256;
#pragma unroll
            for (int oc = 0; oc < 3; ++oc) {
                float m = sm[OSTAT + oc*2], r = sm[OSTAT + oc*2 + 1];
                sm[OPRE + oc*512 + l] = fmaxf((y2[pp][oc] - m) * r * sm[OW+675+oc] + sm[OW+678+oc], 0.f);
            }
        }
        __syncthreads();
        // conv6 (3->1)
        float a6[2];
#pragma unroll
        for (int pp = 0; pp < 2; ++pp) {
            const int l = tid + pp * 256;
            float a = sm[OW + 690];
#pragma unroll
            for (int ic = 0; ic < 3; ++ic) {
                float c0 = (l > 0)   ? sm[OPRE + ic*512 + l - 1] : 0.f;
                float c1 =             sm[OPRE + ic*512 + l];
                float c2 = (l < 511) ? sm[OPRE + ic*512 + l + 1] : 0.f;
                a += sm[OW+681+ic*3]*c0 + sm[OW+681+ic*3+1]*c1 + sm[OW+681+ic*3+2]*c2;
            }
            a6[pp] = a;
            sm[OY + l] = a;
        }
        __syncthreads();
        if (wid == 0) {
            float s = 0.f, s2 = 0.f;
#pragma unroll
            for (int j = 0; j < 8; ++j) { float v = sm[OY + lane + j*64]; s += v; s2 += v*v; }
            s = wave_rsum(s); s2 = wave_rsum(s2);
            if (lane == 0) {
                float m = s * (1.f/512.f), var = s2 * (1.f/512.f) - m*m;
                sm[OSTAT] = m; sm[OSTAT+1] = rsqrtf(var + 1e-5f);
            }
        }
        __syncthreads();
#pragma unroll
        for (int pp = 0; pp < 2; ++pp) {
            const int l = tid + pp * 256;
            ws[WSF_XT + l] = fmaxf((a6[pp] - sm[OSTAT]) * sm[OSTAT+1] * sm[OW+691] + sm[OW+692], 0.f);
        }
    }
    grid.sync();

    // ---------------- P4..P7: GRU layers, block = unit ----------------
#pragma unroll 1
    for (int l = 0; l < 4; ++l) {
        if (wid < 3) {
            const float* xt = ws + WSF_XT + l * 512;
            float xq0[4], xq1[4];
#pragma unroll
            for (int j = 0; j < 4; ++j) { xq0[j] = xt[lane*4 + j]; xq1[j] = xt[256 + lane*4 + j]; }
            const float* wr = P.wih + ((size_t)l * 1536 + wid * 512 + bid) * 512;
            f32x4 w0 = *(const f32x4*)(wr + lane*4);
            f32x4 w1 = *(const f32x4*)(wr + 256 + lane*4);
            float a = 0.f;
#pragma unroll
            for (int j = 0; j < 4; ++j) a += w0[j]*xq0[j] + w1[j]*xq1[j];
            a = wave_rsum(a);
            if (lane == 0) sm[OY + wid] = a + P.bih[l*1536 + wid*512 + bid];
        }
        __syncthreads();
        if (tid == 0) {
            float gr = ws[WSF_GH + l*1536 + bid];
            float gz = ws[WSF_GH + l*1536 + 512 + bid];
            float gn = ws[WSF_GH + l*1536 + 1024 + bid];
            float r = sigm(sm[OY+0] + gr);
            float z = sigm(sm[OY+1] + gz);
            float n = tanhf(sm[OY+2] + r * gn);
            float h = (1.f - z) * n + z * P.hstate[l*512 + bid];
            ws[WSF_XT + (l+1)*512 + bid] = h;
            P.out[NVOCAB + l*512 + bid] = h;
        }
        if (l < 3) grid.sync();
    }
}

// =====================================================================
// FALLBACK kernels (R4-proven path), used if cooperative launch fails
// =====================================================================
__global__ __launch_bounds__(256) void k_gruh(
    const float* __restrict__ whh, const float* __restrict__ bhh,
    const float* __restrict__ hstate, float* __restrict__ ws)
{
    const int tid = threadIdx.x, lane = tid & 63, wid = tid >> 6;
    const int R = blockIdx.x * 4 + wid;
    const int l = R / 1536;
    const float* hp = hstate + l * 512;
    float h0[4], h1[4];
#pragma unroll
    for (int j = 0; j < 4; ++j) { h0[j] = hp[lane*4+j]; h1[j] = hp[256+lane*4+j]; }
    const float* wr = whh + (size_t)R * 512;
    f32x4 w0 = *(const f32x4*)(wr + lane*4);
    f32x4 w1 = *(const f32x4*)(wr + 256 + lane*4);
    float a = 0.f;
#pragma unroll
    for (int j = 0; j < 4; ++j) a += w0[j]*h0[j] + w1[j]*h1[j];
    a = wave_rsum(a);
    if (lane == 0) ws[WSF_GH + R] = a + bhh[R];
}

__global__ __launch_bounds__(512) void k_pre(
    const float* __restrict__ emb, const int* __restrict__ xidx,
    const float* __restrict__ hstate,
    const float* __restrict__ w1, const float* __restrict__ b1,
    const float* __restrict__ w2, const float* __restrict__ b2,
    const float* __restrict__ w3, const float* __restrict__ b3,
    const float* __restrict__ g1, const float* __restrict__ bb1,
    const float* __restrict__ g2, const float* __restrict__ bb2,
    const float* __restrict__ g3, const float* __restrict__ bb3,
    float* __restrict__ ws)
{
    constexpr int W1 = 0, B1 = 480, G1 = 512, BB1 = 544;
    constexpr int W2 = 576, B2 = 1056, G2 = 1061, BB2 = 1066;
    constexpr int W3 = 1071, B3 = 1086, G3 = 1087, BB3 = 1088, NW = 1089;
    __shared__ float s_w[NW];
    __shared__ float s_pre[5][512];
    __shared__ float s_y[32][512];
    __shared__ float s_stat[32][2];
    const int tid = threadIdx.x, lane = tid & 63, wid = tid >> 6, l = tid;
    if (tid < 480) s_w[W1 + tid] = w1[tid];
    if (tid < 32) { s_w[B1 + tid] = b1[tid]; s_w[G1 + tid] = g1[tid]; s_w[BB1 + tid] = bb1[tid]; }
    if (tid < 480) s_w[W2 + tid] = w2[tid];
    if (tid < 5) { s_w[B2 + tid] = b2[tid]; s_w[G2 + tid] = g2[tid]; s_w[BB2 + tid] = bb2[tid]; }
    if (tid < 15) s_w[W3 + tid] = w3[tid];
    if (tid == 0) { s_w[B3] = b3[0]; s_w[G3] = g3[0]; s_w[BB3] = bb3[0]; }
    const int x = xidx[0];
#pragma unroll
    for (int c = 0; c < 4; ++c) s_pre[c][l] = hstate[c * 512 + l];
    s_pre[4][l] = emb[(size_t)x * 512 + l];
    __syncthreads();
    float px[5][3];
#pragma unroll
    for (int ic = 0; ic < 5; ++ic) {
        px[ic][0] = (l > 0) ? s_pre[ic][l-1] : 0.f;
        px[ic][1] = s_pre[ic][l];
        px[ic][2] = (l < 511) ? s_pre[ic][l+1] : 0.f;
    }
#pragma unroll 4
    for (int oc = 0; oc < 32; ++oc) {
        float a = s_w[B1 + oc];
#pragma unroll
        for (int ic = 0; ic < 5; ++ic)
#pragma unroll
            for (int k = 0; k < 3; ++k) a += s_w[W1 + oc*15 + ic*3 + k] * px[ic][k];
        s_y[oc][l] = a;
    }
    __syncthreads();
#pragma unroll
    for (int t = 0; t < 4; ++t) {
        const int oc = wid * 4 + t;
        float s = 0.f, s2 = 0.f;
#pragma unroll
        for (int j = 0; j < 8; ++j) { float v = s_y[oc][lane + j*64]; s += v; s2 += v*v; }
        s = wave_rsum(s); s2 = wave_rsum(s2);
        if (lane == 0) { float m = s/512.f, var = s2/512.f - m*m; s_stat[oc][0] = m; s_stat[oc][1] = rsqrtf(var + 1e-5f); }
    }
    __syncthreads();
#pragma unroll 4
    for (int oc = 0; oc < 32; ++oc)
        s_y[oc][l] = fmaxf((s_y[oc][l] - s_stat[oc][0]) * s_stat[oc][1] * s_w[G1+oc] + s_w[BB1+oc], 0.f);
    __syncthreads();
    float y2[5];
#pragma unroll
    for (int oc = 0; oc < 5; ++oc) y2[oc] = s_w[B2 + oc];
#pragma unroll 2
    for (int ic = 0; ic < 32; ++ic) {
        float c0 = (l > 0) ? s_y[ic][l-1] : 0.f;
        float c1 = s_y[ic][l];
        float c2 = (l < 511) ? s_y[ic][l+1] : 0.f;
#pragma unroll
        for (int oc = 0; oc < 5; ++oc) {
            const int base = W2 + (oc*32 + ic)*3;
            y2[oc] += s_w[base]*c0 + s_w[base+1]*c1 + s_w[base+2]*c2;
        }
    }
#pragma unroll
    for (int oc = 0; oc < 5; ++oc) y2[oc] += s_pre[oc][l];
    __syncthreads();
#pragma unroll
    for (int oc = 0; oc < 5; ++oc) s_y[oc][l] = y2[oc];
    __syncthreads();
    if (wid < 5) {
        const int oc = wid;
        float s = 0.f, s2 = 0.f;
#pragma unroll
        for (int j = 0; j < 8; ++j) { float v = s_y[oc][lane + j*64]; s += v; s2 += v*v; }
        s = wave_rsum(s); s2 = wave_rsum(s2);
        if (lane == 0) { float m = s/512.f, var = s2/512.f - m*m; s_stat[oc][0] = m; s_stat[oc][1] = rsqrtf(var + 1e-5f); }
    }
    __syncthreads();
#pragma unroll
    for (int oc = 0; oc < 5; ++oc)
        s_pre[oc][l] = fmaxf((y2[oc] - s_stat[oc][0]) * s_stat[oc][1] * s_w[G2+oc] + s_w[BB2+oc], 0.f);
    __syncthreads();
    float a3 = s_w[B3];
#pragma unroll
    for (int ic = 0; ic < 5; ++ic) {
        float c0 = (l > 0) ? s_pre[ic][l-1] : 0.f;
        float c1 = s_pre[ic][l];
        float c2 = (l < 511) ? s_pre[ic][l+1] : 0.f;
        a3 += s_w[W3+ic*3]*c0 + s_w[W3+ic*3+1]*c1 + s_w[W3+ic*3+2]*c2;
    }
    s_y[0][l] = a3;
    __syncthreads();
    if (wid == 0) {
        float s = 0.f, s2 = 0.f;
#pragma unroll
        for (int j = 0; j < 8; ++j) { float v = s_y[0][lane + j*64]; s += v; s2 += v*v; }
        s = wave_rsum(s); s2 = wave_rsum(s2);
        if (lane == 0) { float m = s/512.f, var = s2/512.f - m*m; s_stat[0][0] = m; s_stat[0][1] = rsqrtf(var + 1e-5f); }
    }
    __syncthreads();
    ws[WSF_Q + l] = fmaxf((a3 - s_stat[0][0]) * s_stat[0][1] * s_w[G3] + s_w[BB3], 0.f);
}

__global__ __launch_bounds__(256) void k_attlogit(
    const float* __restrict__ attw, const float* __restrict__ attb,
    float* __restrict__ ws)
{
    __shared__ float s_l[16];
    const int tid = threadIdx.x, lane = tid & 63, wid = tid >> 6;
    float q0[4], q1[4];
#pragma unroll
    for (int j = 0; j < 4; ++j) { q0[j] = ws[WSF_Q + lane*4 + j]; q1[j] = ws[WSF_Q + 256 + lane*4 + j]; }
    const int row0 = (blockIdx.x * 4 + wid) * 4;
#pragma unroll
    for (int r = 0; r < 4; ++r) {
        const int row = row0 + r;
        f32x4 w0 = *(const f32x4*)(attw + (size_t)row*512 + lane*4);
        f32x4 w1 = *(const f32x4*)(attw + (size_t)row*512 + 256 + lane*4);
        float a = 0.f;
#pragma unroll
        for (int j = 0; j < 4; ++j) a += w0[j]*q0[j] + w1[j]*q1[j];
        a = wave_rsum(a);
        if (lane == 0) { float v = a + attb[row]; ws[WSF_LOGA + row] = v; s_l[wid*4+r] = v; }
    }
    __syncthreads();
    if (tid == 0) {
        float m = -INFINITY;
#pragma unroll
        for (int k = 0; k < 16; ++k) m = fmaxf(m, s_l[k]);
        float s = 0.f;
#pragma unroll
        for (int k = 0; k < 16; ++k) s += __expf(s_l[k] - m);
        ws[WSF_ATTM + blockIdx.x] = m; ws[WSF_ATTS + blockIdx.x] = s;
    }
}

__global__ __launch_bounds__(256) void k_attpv(
    const float* __restrict__ enc, float* __restrict__ ws)
{
    const int tid = threadIdx.x;
    float M = -INFINITY, S = 0.f;
    for (int i = 0; i < 128; ++i) {
        float mb = ws[WSF_ATTM + i], sb = ws[WSF_ATTS + i];
        if (mb > M) { S = S * __expf(M - mb) + sb; M = mb; }
        else        { S += sb * __expf(mb - M); }
    }
    const int jc = blockIdx.x >> 1, half = blockIdx.x & 1;
    __shared__ float s_e[64];
    if (tid < 64) s_e[tid] = __expf(ws[WSF_LOGA + jc*64 + tid] - M);
    __syncthreads();
    const int col = half * 512 + tid * 2;
    const float* ep = enc + (size_t)(jc*64) * 1024 + col;
    float a0 = 0.f, a1 = 0.f;
#pragma unroll 4
    for (int jj = 0; jj < 64; ++jj) {
        float2 e = *(const float2*)(ep + (size_t)jj * 1024);
        a0 += s_e[jj] * e.x; a1 += s_e[jj] * e.y;
    }
    ws[WSF_PARTF + jc*1024 + col] = a0;
    ws[WSF_PARTF + jc*1024 + col + 1] = a1;
}

__global__ __launch_bounds__(512) void k_post(
    const float* __restrict__ emb, const int* __restrict__ xidx,
    const float* __restrict__ w4, const float* __restrict__ b4,
    const float* __restrict__ w5, const float* __restrict__ b5,
    const float* __restrict__ w6, const float* __restrict__ b6,
    const float* __restrict__ g4, const float* __restrict__ bb4,
    const float* __restrict__ g5, const float* __restrict__ bb5,
    const float* __restrict__ g6, const float* __restrict__ bb6,
    float* __restrict__ ws)
{
    constexpr int W4 = 0, B4 = 288, G4 = 320, BB4 = 352;
    constexpr int W5 = 384, B5 = 672, G5 = 675, BB5 = 678;
    constexpr int W6 = 681, B6 = 690, G6 = 691, BB6 = 692, NW = 693;
    __shared__ float s_w[NW];
    __shared__ float s_com[3][512];
    __shared__ float s_y[32][512];
    __shared__ float s_stat[32][2];
    const int tid = threadIdx.x, lane = tid & 63, wid = tid >> 6, l = tid;
    if (tid < 288) s_w[W4 + tid] = w4[tid];
    if (tid < 32) { s_w[B4 + tid] = b4[tid]; s_w[G4 + tid] = g4[tid]; s_w[BB4 + tid] = bb4[tid]; }
    if (tid < 288) s_w[W5 + tid] = w5[tid];
    if (tid < 3) { s_w[B5 + tid] = b5[tid]; s_w[G5 + tid] = g5[tid]; s_w[BB5 + tid] = bb5[tid]; }
    if (tid < 9) s_w[W6 + tid] = w6[tid];
    if (tid == 0) { s_w[B6] = b6[0]; s_w[G6] = g6[0]; s_w[BB6] = bb6[0]; }
    float M = -INFINITY, S = 0.f;
    for (int i = 0; i < 128; ++i) {
        float mb = ws[WSF_ATTM + i], sb = ws[WSF_ATTS + i];
        if (mb > M) { S = S * __expf(M - mb) + sb; M = mb; }
        else        { S += sb * __expf(mb - M); }
    }
    const float invS = 1.0f / S;
    float a0 = 0.f, a1 = 0.f;
#pragma unroll 8
    for (int p = 0; p < 32; ++p) { a0 += ws[WSF_PARTF + p*1024 + l]; a1 += ws[WSF_PARTF + p*1024 + 512 + l]; }
    const int x = xidx[0];
    s_com[0][l] = a0 * invS; s_com[1][l] = a1 * invS; s_com[2][l] = emb[(size_t)x*512 + l];
    __syncthreads();
    float px[3][3];
#pragma unroll
    for (int ic = 0; ic < 3; ++ic) {
        px[ic][0] = (l > 0) ? s_com[ic][l-1] : 0.f;
        px[ic][1] = s_com[ic][l];
        px[ic][2] = (l < 511) ? s_com[ic][l+1] : 0.f;
    }
#pragma unroll 4
    for (int oc = 0; oc < 32; ++oc) {
        float a = s_w[B4 + oc];
#pragma unroll
        for (int ic = 0; ic < 3; ++ic)
#pragma unroll
            for (int k = 0; k < 3; ++k) a += s_w[W4 + oc*9 + ic*3 + k] * px[ic][k];
        s_y[oc][l] = a;
    }
    __syncthreads();
#pragma unroll
    for (int t = 0; t < 4; ++t) {
        const int oc = wid * 4 + t;
        float s = 0.f, s2 = 0.f;
#pragma unroll
        for (int j = 0; j < 8; ++j) { float v = s_y[oc][lane + j*64]; s += v; s2 += v*v; }
        s = wave_rsum(s); s2 = wave_rsum(s2);
        if (lane == 0) { float m = s/512.f, var = s2/512.f - m*m; s_stat[oc][0] = m; s_stat[oc][1] = rsqrtf(var + 1e-5f); }
    }
    __syncthreads();
#pragma unroll 4
    for (int oc = 0; oc < 32; ++oc)
        s_y[oc][l] = fmaxf((s_y[oc][l] - s_stat[oc][0]) * s_stat[oc][1] * s_w[G4+oc] + s_w[BB4+oc], 0.f);
    __syncthreads();
    float y2[3];
#pragma unroll
    for (int oc = 0; oc < 3; ++oc) y2[oc] = s_w[B5 + oc];
#pragma unroll 2
    for (int ic = 0; ic < 32; ++ic) {
        float c0 = (l > 0) ? s_y[ic][l-1] : 0.f;
        float c1 = s_y[ic][l];
        float c2 = (l < 511) ? s_y[ic][l+1] : 0.f;
#pragma unroll
        for (int oc = 0; oc < 3; ++oc) {
            const int base = W5 + (oc*32 + ic)*3;
            y2[oc] += s_w[base]*c0 + s_w[base+1]*c1 + s_w[base+2]*c2;
        }
    }
#pragma unroll
    for (int oc = 0; oc < 3; ++oc) y2[oc] += s_com[oc][l];
    __syncthreads();
#pragma unroll
    for (int oc = 0; oc < 3; ++oc) s_y[oc][l] = y2[oc];
    __syncthreads();
    if (wid < 3) {
        const int oc = wid;
        float s = 0.f, s2 = 0.f;
#pragma unroll
        for (int j = 0; j < 8; ++j) { float v = s_y[oc][lane + j*64]; s += v; s2 += v*v; }
        s = wave_rsum(s); s2 = wave_rsum(s2);
        if (lane == 0) { float m = s/512.f, var = s2/512.f - m*m; s_stat[oc][0] = m; s_stat[oc][1] = rsqrtf(var + 1e-5f); }
    }
    __syncthreads();
#pragma unroll
    for (int oc = 0; oc < 3; ++oc)
        s_com[oc][l] = fmaxf((y2[oc] - s_stat[oc][0]) * s_stat[oc][1] * s_w[G5+oc] + s_w[BB5+oc], 0.f);
    __syncthreads();
    float a6 = s_w[B6];
#pragma unroll
    for (int ic = 0; ic < 3; ++ic) {
        float c0 = (l > 0) ? s_com[ic][l-1] : 0.f;
        float c1 = s_com[ic][l];
        float c2 = (l < 511) ? s_com[ic][l+1] : 0.f;
        a6 += s_w[W6+ic*3]*c0 + s_w[W6+ic*3+1]*c1 + s_w[W6+ic*3+2]*c2;
    }
    s_y[0][l] = a6;
    __syncthreads();
    if (wid == 0) {
        float s = 0.f, s2 = 0.f;
#pragma unroll
        for (int j = 0; j < 8; ++j) { float v = s_y[0][lane + j*64]; s += v; s2 += v*v; }
        s = wave_rsum(s); s2 = wave_rsum(s2);
        if (lane == 0) { float m = s/512.f, var = s2/512.f - m*m; s_stat[0][0] = m; s_stat[0][1] = rsqrtf(var + 1e-5f); }
    }
    __syncthreads();
    ws[WSF_XT + l] = fmaxf((a6 - s_stat[0][0]) * s_stat[0][1] * s_w[G6] + s_w[BB6], 0.f);
}

__global__ __launch_bounds__(256) void k_grux(
    const float* __restrict__ wih, const float* __restrict__ bih,
    const float* __restrict__ hstate,
    const float* __restrict__ xt_in, float* __restrict__ xt_out,
    float* __restrict__ hout, const float* __restrict__ gh, int layer)
{
    wih += (size_t)layer * 1536 * 512;
    bih += layer * 1536;
    const float* hp = hstate + layer * 512;
    const int tid = threadIdx.x, lane = tid & 63, wid = tid >> 6;
    float xq0[4], xq1[4];
#pragma unroll
    for (int j = 0; j < 4; ++j) { xq0[j] = xt_in[lane*4+j]; xq1[j] = xt_in[256+lane*4+j]; }
    __shared__ float s_g[4][3];
    const int u = blockIdx.x * 4 + wid;
#pragma unroll
    for (int g = 0; g < 3; ++g) {
        const float* wr = wih + (size_t)(u + g*512) * 512;
        f32x4 w0 = *(const f32x4*)(wr + lane*4);
        f32x4 w1 = *(const f32x4*)(wr + 256 + lane*4);
        float a = 0.f;
#pragma unroll
        for (int j = 0; j < 4; ++j) a += w0[j]*xq0[j] + w1[j]*xq1[j];
        a = wave_rsum(a);
        if (lane == 0) s_g[wid][g] = a + bih[u + g*512];
    }
    __syncthreads();
    if (tid < 4) {
        const int i = blockIdx.x * 4 + tid;
        float r = sigm(s_g[tid][0] + gh[i]);
        float z = sigm(s_g[tid][1] + gh[i + 512]);
        float n = tanhf(s_g[tid][2] + r * gh[i + 1024]);
        float h = (1.f - z) * n + z * hp[i];
        xt_out[i] = h;
        hout[i] = h;
    }
}

// =====================================================================
// K5: vocab GEMV + per-block online (max, sum-exp).  786 blocks x 256
// =====================================================================
__global__ __launch_bounds__(256) void k_vocab(
    const float* __restrict__ low, const float* __restrict__ lob,
    float* __restrict__ ws)
{
    const int tid = threadIdx.x, lane = tid & 63, wid = tid >> 6;
    float q0[4], q1[4];
#pragma unroll
    for (int j = 0; j < 4; ++j) {
        q0[j] = ws[WSF_XT + 4*512 + lane*4 + j];
        q1[j] = ws[WSF_XT + 4*512 + 256 + lane*4 + j];
    }
    const int row0 = blockIdx.x * 64 + wid * 16;
    float m = -INFINITY, s = 0.0f;
#pragma unroll 4
    for (int r = 0; r < 16; ++r) {
        const int row = row0 + r;
        if (row < NVOCAB) {
            f32x4 w0 = *(const f32x4*)(low + (size_t)row*512 + lane*4);
            f32x4 w1 = *(const f32x4*)(low + (size_t)row*512 + 256 + lane*4);
            float a = 0.f;
#pragma unroll
            for (int j = 0; j < 4; ++j) a += w0[j]*q0[j] + w1[j]*q1[j];
            a = wave_rsum(a);
            if (lane == 0) {
                float v = a + lob[row];
                ws[WSF_LOGV + row] = v;
                if (v > m) { s = s * __expf(m - v) + 1.0f; m = v; }
                else       { s += __expf(v - m); }
            }
        }
    }
    __shared__ float smx[4], ssx[4];
    if (lane == 0) { smx[wid] = m; ssx[wid] = s; }
    __syncthreads();
    if (tid == 0) {
        float M = -INFINITY, S = 0.0f;
#pragma unroll
        for (int w = 0; w < 4; ++w) {
            float mb = smx[w], sb = ssx[w];
            if (sb > 0.0f) {
                if (mb > M) { S = S * __expf(M - mb) + sb; M = mb; }
                else        { S += sb * __expf(mb - M); }
            }
        }
        ws[WSF_PM + blockIdx.x] = M;
        ws[WSF_PS + blockIdx.x] = S;
    }
}

// =====================================================================
// K6: redundant deterministic LSE + write log-probs.  197 blocks x 256
// =====================================================================
__global__ __launch_bounds__(256) void k_outlse(
    const float* __restrict__ ws, float* __restrict__ out)
{
    __shared__ float smx[256], ssx[256];
    const int tid = threadIdx.x;
    float M = -INFINITY, S = 0.0f;
    for (int i = tid; i < NBLK_V; i += 256) {
        float mb = ws[WSF_PM + i], sb = ws[WSF_PS + i];
        if (mb > M) { S = S * __expf(M - mb) + sb; M = mb; }
        else        { S += sb * __expf(mb - M); }
    }
    smx[tid] = M; ssx[tid] = S;
    __syncthreads();
    for (int st = 128; st > 0; st >>= 1) {
        if (tid < st) {
            float mb = smx[tid + st], sb = ssx[tid + st];
            if (sb > 0.0f) {
                if (mb > smx[tid]) { ssx[tid] = ssx[tid] * __expf(smx[tid] - mb) + sb; smx[tid] = mb; }
                else               { ssx[tid] += sb * __expf(mb - smx[tid]); }
            }
        }
        __syncthreads();
    }
    const float lse = smx[0] + logf(ssx[0]);
    const int i = blockIdx.x * 256 + tid;
    if (i < NVOCAB) out[i] = ws[WSF_LOGV + i] - lse;
}

// =====================================================================
extern "C" void kernel_launch(void* const* d_in, const int* in_sizes, int n_in,
                              void* d_out, int out_size, void* d_ws, size_t ws_size,
                              hipStream_t stream)
{
    (void)in_sizes; (void)n_in; (void)out_size; (void)ws_size;
    const float* emb     = (const float*)d_in[0];
    const float* conv1_w = (const float*)d_in[1];  const float* conv1_b = (const float*)d_in[2];
    const float* conv2_w = (const float*)d_in[3];  const float* conv2_b = (const float*)d_in[4];
    const float* conv3_w = (const float*)d_in[5];  const float* conv3_b = (const float*)d_in[6];
    const float* conv4_w = (const float*)d_in[7];  const float* conv4_b = (const float*)d_in[8];
    const float* conv5_w = (const float*)d_in[9];  const float* conv5_b = (const float*)d_in[10];
    const float* conv6_w = (const float*)d_in[11]; const float* conv6_b = (const float*)d_in[12];
    const float* bn1_g = (const float*)d_in[13];   const float* bn1_b = (const float*)d_in[14];
    const float* bn2_g = (const float*)d_in[15];   const float* bn2_b = (const float*)d_in[16];
    const float* bn3_g = (const float*)d_in[17];   const float* bn3_b = (const float*)d_in[18];
    const float* bn4_g = (const float*)d_in[19];   const float* bn4_b = (const float*)d_in[20];
    const float* bn5_g = (const float*)d_in[21];   const float* bn5_b = (const float*)d_in[22];
    const float* bn6_g = (const float*)d_in[23];   const float* bn6_b = (const float*)d_in[24];
    const float* att_w = (const float*)d_in[25];   const float* att_b = (const float*)d_in[26];
    const float* gru_wih = (const float*)d_in[27]; const float* gru_whh = (const float*)d_in[28];
    const float* gru_bih = (const float*)d_in[29]; const float* gru_bhh = (const float*)d_in[30];
    const float* lo_w = (const float*)d_in[31];    const float* lo_b = (const float*)d_in[32];
    const float* h_state = (const float*)d_in[33];
    const float* enc = (const float*)d_in[34];
    const int* x = (const int*)d_in[35];

    float* ws = (float*)d_ws;
    float* out = (float*)d_out;

    KParams hp;
    hp.emb = emb;
    hp.c1w = conv1_w; hp.c1b = conv1_b; hp.c2w = conv2_w; hp.c2b = conv2_b;
    hp.c3w = conv3_w; hp.c3b = conv3_b; hp.c4w = conv4_w; hp.c4b = conv4_b;
    hp.c5w = conv5_w; hp.c5b = conv5_b; hp.c6w = conv6_w; hp.c6b = conv6_b;
    hp.g1 = bn1_g; hp.bb1 = bn1_b; hp.g2 = bn2_g; hp.bb2 = bn2_b;
    hp.g3 = bn3_g; hp.bb3 = bn3_b; hp.g4 = bn4_g; hp.bb4 = bn4_b;
    hp.g5 = bn5_g; hp.bb5 = bn5_b; hp.g6 = bn6_g; hp.bb6 = bn6_b;
    hp.attw = att_w; hp.attb = att_b;
    hp.wih = gru_wih; hp.whh = gru_whh; hp.bih = gru_bih; hp.bhh = gru_bhh;
    hp.hstate = h_state; hp.enc = enc; hp.x = x;
    hp.ws = ws; hp.out = out;

    void* args[] = { &hp };
    hipError_t e = hipLaunchCooperativeKernel((const void*)k_head, dim3(512), dim3(256),
                                              args, 0, stream);
    if (e != hipSuccess) {
        // fallback: proven multi-kernel path
        k_gruh<<<1536, 256, 0, stream>>>(gru_whh, gru_bhh, h_state, ws);
        k_pre<<<1, 512, 0, stream>>>(emb, x, h_state,
            conv1_w, conv1_b, conv2_w, conv2_b, conv3_w, conv3_b,
            bn1_g, bn1_b, bn2_g, bn2_b, bn3_g, bn3_b, ws);
        k_attlogit<<<128, 256, 0, stream>>>(att_w, att_b, ws);
        k_attpv<<<64, 256, 0, stream>>>(enc, ws);
        k_post<<<1, 512, 0, stream>>>(emb, x,
            conv4_w, conv4_b, conv5_w, conv5_b, conv6_w, conv6_b,
            bn4_g, bn4_b, bn5_g, bn5_b, bn6_g, bn6_b, ws);
        for (int l = 0; l < 4; ++l) {
            k_grux<<<128, 256, 0, stream>>>(gru_wih, gru_bih, h_state,
                ws + WSF_XT + l * 512, ws + WSF_XT + (l + 1) * 512,
                out + NVOCAB + l * 512, ws + WSF_GH + l * 1536, l);
        }
    }
    k_vocab<<<NBLK_V, 256, 0, stream>>>(lo_w, lo_b, ws);
    k_outlse<<<197, 256, 0, stream>>>(ws, out);
}

// Round 6
// 96.564 us; speedup vs baseline: 4.8747x; 4.8747x over previous
//
#include <hip/hip_runtime.h>
#include <hip/hip_bf16.h>

typedef __attribute__((ext_vector_type(4))) float f32x4;

// ---------------- workspace layout (fp32 elements) ----------------
constexpr int WSF_Q     = 0;        // 512    attention query (conv3 out)
constexpr int WSF_ADEN  = 512;      // 32     per-chunk exp-sum
constexpr int WSF_APART = 1024;     // 32*1024 per-chunk PV partials (unnormalized)
constexpr int WSF_XT    = 33792;    // 5*512  xt chain
constexpr int WSF_LOGV  = 36352;    // 50257  vocab logits
constexpr int WSF_PM    = 86624;    // 786    per-block max
constexpr int WSF_PS    = 87424;    // 786    per-block sum-exp
constexpr int NVOCAB    = 50257;
constexpr int NBLK_V    = 786;      // ceil(50257/64)

__device__ __forceinline__ float wave_rsum(float v) {
#pragma unroll
    for (int o = 32; o > 0; o >>= 1) v += __shfl_down(v, o);
    return v; // lane 0 holds sum
}
__device__ __forceinline__ float sigm(float x) { return 1.0f / (1.0f + __expf(-x)); }

// =====================================================================
// K1: pre-attention conv stack.  1 block x 512 threads (thread = position)
// =====================================================================
__global__ __launch_bounds__(512) void k_pre(
    const float* __restrict__ emb, const int* __restrict__ xidx,
    const float* __restrict__ hstate,
    const float* __restrict__ w1, const float* __restrict__ b1,
    const float* __restrict__ w2, const float* __restrict__ b2,
    const float* __restrict__ w3, const float* __restrict__ b3,
    const float* __restrict__ g1, const float* __restrict__ bb1,
    const float* __restrict__ g2, const float* __restrict__ bb2,
    const float* __restrict__ g3, const float* __restrict__ bb3,
    float* __restrict__ ws)
{
    constexpr int W1 = 0, B1 = 480, G1 = 512, BB1 = 544;
    constexpr int W2 = 576, B2 = 1056, G2 = 1061, BB2 = 1066;
    constexpr int W3 = 1071, B3 = 1086, G3 = 1087, BB3 = 1088, NW = 1089;
    __shared__ float s_w[NW];
    __shared__ float s_pre[5][512];
    __shared__ float s_y[32][512];
    __shared__ float s_stat[32][2];
    const int tid = threadIdx.x, lane = tid & 63, wid = tid >> 6, l = tid;

    if (tid < 480) s_w[W1 + tid] = w1[tid];
    if (tid < 32) { s_w[B1 + tid] = b1[tid]; s_w[G1 + tid] = g1[tid]; s_w[BB1 + tid] = bb1[tid]; }
    if (tid < 480) s_w[W2 + tid] = w2[tid];
    if (tid < 5) { s_w[B2 + tid] = b2[tid]; s_w[G2 + tid] = g2[tid]; s_w[BB2 + tid] = bb2[tid]; }
    if (tid < 15) s_w[W3 + tid] = w3[tid];
    if (tid == 0) { s_w[B3] = b3[0]; s_w[G3] = g3[0]; s_w[BB3] = bb3[0]; }

    const int x = xidx[0];
#pragma unroll
    for (int c = 0; c < 4; ++c) s_pre[c][l] = hstate[c * 512 + l];
    s_pre[4][l] = emb[(size_t)x * 512 + l];
    __syncthreads();

    // ---- conv1 (5->32) ----
    float px[5][3];
#pragma unroll
    for (int ic = 0; ic < 5; ++ic) {
        px[ic][0] = (l > 0)   ? s_pre[ic][l-1] : 0.f;
        px[ic][1] =             s_pre[ic][l];
        px[ic][2] = (l < 511) ? s_pre[ic][l+1] : 0.f;
    }
#pragma unroll 4
    for (int oc = 0; oc < 32; ++oc) {
        float a = s_w[B1 + oc];
#pragma unroll
        for (int ic = 0; ic < 5; ++ic)
#pragma unroll
            for (int k = 0; k < 3; ++k)
                a += s_w[W1 + oc*15 + ic*3 + k] * px[ic][k];
        s_y[oc][l] = a;
    }
    __syncthreads();
#pragma unroll
    for (int t = 0; t < 4; ++t) {
        const int oc = wid * 4 + t;
        float s = 0.f, s2 = 0.f;
#pragma unroll
        for (int j = 0; j < 8; ++j) { float v = s_y[oc][lane + j*64]; s += v; s2 += v*v; }
        s = wave_rsum(s); s2 = wave_rsum(s2);
        if (lane == 0) { float m = s/512.f, var = s2/512.f - m*m; s_stat[oc][0] = m; s_stat[oc][1] = rsqrtf(var + 1e-5f); }
    }
    __syncthreads();
#pragma unroll 4
    for (int oc = 0; oc < 32; ++oc)
        s_y[oc][l] = fmaxf((s_y[oc][l] - s_stat[oc][0]) * s_stat[oc][1] * s_w[G1+oc] + s_w[BB1+oc], 0.f);
    __syncthreads();

    // ---- conv2 (32->5) + residual ----
    float y2[5];
#pragma unroll
    for (int oc = 0; oc < 5; ++oc) y2[oc] = s_w[B2 + oc];
#pragma unroll 2
    for (int ic = 0; ic < 32; ++ic) {
        float c0 = (l > 0)   ? s_y[ic][l-1] : 0.f;
        float c1 =             s_y[ic][l];
        float c2 = (l < 511) ? s_y[ic][l+1] : 0.f;
#pragma unroll
        for (int oc = 0; oc < 5; ++oc) {
            const int base = W2 + (oc*32 + ic)*3;
            y2[oc] += s_w[base]*c0 + s_w[base+1]*c1 + s_w[base+2]*c2;
        }
    }
#pragma unroll
    for (int oc = 0; oc < 5; ++oc) y2[oc] += s_pre[oc][l];
    __syncthreads();
#pragma unroll
    for (int oc = 0; oc < 5; ++oc) s_y[oc][l] = y2[oc];
    __syncthreads();
    if (wid < 5) {
        const int oc = wid;
        float s = 0.f, s2 = 0.f;
#pragma unroll
        for (int j = 0; j < 8; ++j) { float v = s_y[oc][lane + j*64]; s += v; s2 += v*v; }
        s = wave_rsum(s); s2 = wave_rsum(s2);
        if (lane == 0) { float m = s/512.f, var = s2/512.f - m*m; s_stat[oc][0] = m; s_stat[oc][1] = rsqrtf(var + 1e-5f); }
    }
    __syncthreads();
#pragma unroll
    for (int oc = 0; oc < 5; ++oc)
        s_pre[oc][l] = fmaxf((y2[oc] - s_stat[oc][0]) * s_stat[oc][1] * s_w[G2+oc] + s_w[BB2+oc], 0.f);
    __syncthreads();

    // ---- conv3 (5->1) ----
    float a3 = s_w[B3];
#pragma unroll
    for (int ic = 0; ic < 5; ++ic) {
        float c0 = (l > 0)   ? s_pre[ic][l-1] : 0.f;
        float c1 =             s_pre[ic][l];
        float c2 = (l < 511) ? s_pre[ic][l+1] : 0.f;
        a3 += s_w[W3+ic*3]*c0 + s_w[W3+ic*3+1]*c1 + s_w[W3+ic*3+2]*c2;
    }
    s_y[0][l] = a3;
    __syncthreads();
    if (wid == 0) {
        float s = 0.f, s2 = 0.f;
#pragma unroll
        for (int j = 0; j < 8; ++j) { float v = s_y[0][lane + j*64]; s += v; s2 += v*v; }
        s = wave_rsum(s); s2 = wave_rsum(s2);
        if (lane == 0) { float m = s/512.f, var = s2/512.f - m*m; s_stat[0][0] = m; s_stat[0][1] = rsqrtf(var + 1e-5f); }
    }
    __syncthreads();
    ws[WSF_Q + l] = fmaxf((a3 - s_stat[0][0]) * s_stat[0][1] * s_w[G3] + s_w[BB3], 0.f);
}

// =====================================================================
// K2: fused attention.  32 blocks x 256.  Block jc: computes its own 64
// logits (rows jc*64..+63), exps (no max; |logit|<~2 validated R5),
// partial denominator, and unnormalized PV partial over all 1024 cols.
// =====================================================================
__global__ __launch_bounds__(256) void k_att(
    const float* __restrict__ attw, const float* __restrict__ attb,
    const float* __restrict__ enc, float* __restrict__ ws)
{
    __shared__ float s_e[64];
    __shared__ float s_d[4];
    const int tid = threadIdx.x, lane = tid & 63, wid = tid >> 6;
    const int jc = blockIdx.x;

    float q0[4], q1[4];
#pragma unroll
    for (int j = 0; j < 4; ++j) {
        q0[j] = ws[WSF_Q + lane*4 + j];
        q1[j] = ws[WSF_Q + 256 + lane*4 + j];
    }
    float dpart = 0.f;
#pragma unroll 4
    for (int r = 0; r < 16; ++r) {
        const int row = jc * 64 + wid * 16 + r;
        f32x4 w0 = *(const f32x4*)(attw + (size_t)row*512 + lane*4);
        f32x4 w1 = *(const f32x4*)(attw + (size_t)row*512 + 256 + lane*4);
        float a = 0.f;
#pragma unroll
        for (int j = 0; j < 4; ++j) a += w0[j]*q0[j] + w1[j]*q1[j];
        a = wave_rsum(a);
        if (lane == 0) {
            float e = __expf(a + attb[row]);
            s_e[wid*16 + r] = e;
            dpart += e;
        }
    }
    if (lane == 0) s_d[wid] = dpart;
    __syncthreads();
    if (tid == 0) ws[WSF_ADEN + jc] = s_d[0] + s_d[1] + s_d[2] + s_d[3];

    // PV partial: thread owns 4 cols
    const int col = tid * 4;
    const float* ep = enc + (size_t)(jc * 64) * 1024 + col;
    f32x4 acc = {0.f, 0.f, 0.f, 0.f};
#pragma unroll 8
    for (int jj = 0; jj < 64; ++jj) {
        f32x4 v = *(const f32x4*)(ep + (size_t)jj * 1024);
        acc += s_e[jj] * v;
    }
    *(f32x4*)(ws + WSF_APART + jc * 1024 + col) = acc;
}

// =====================================================================
// K3: post-attention conv stack.  1 block x 512 threads
// =====================================================================
__global__ __launch_bounds__(512) void k_post(
    const float* __restrict__ emb, const int* __restrict__ xidx,
    const float* __restrict__ w4, const float* __restrict__ b4,
    const float* __restrict__ w5, const float* __restrict__ b5,
    const float* __restrict__ w6, const float* __restrict__ b6,
    const float* __restrict__ g4, const float* __restrict__ bb4,
    const float* __restrict__ g5, const float* __restrict__ bb5,
    const float* __restrict__ g6, const float* __restrict__ bb6,
    float* __restrict__ ws)
{
    constexpr int W4 = 0, B4 = 288, G4 = 320, BB4 = 352;
    constexpr int W5 = 384, B5 = 672, G5 = 675, BB5 = 678;
    constexpr int W6 = 681, B6 = 690, G6 = 691, BB6 = 692, NW = 693;
    __shared__ float s_w[NW];
    __shared__ float s_com[3][512];
    __shared__ float s_y[32][512];
    __shared__ float s_stat[32][2];
    const int tid = threadIdx.x, lane = tid & 63, wid = tid >> 6, l = tid;

    if (tid < 288) s_w[W4 + tid] = w4[tid];
    if (tid < 32) { s_w[B4 + tid] = b4[tid]; s_w[G4 + tid] = g4[tid]; s_w[BB4 + tid] = bb4[tid]; }
    if (tid < 288) s_w[W5 + tid] = w5[tid];
    if (tid < 3) { s_w[B5 + tid] = b5[tid]; s_w[G5 + tid] = g5[tid]; s_w[BB5 + tid] = bb5[tid]; }
    if (tid < 9) s_w[W6 + tid] = w6[tid];
    if (tid == 0) { s_w[B6] = b6[0]; s_w[G6] = g6[0]; s_w[BB6] = bb6[0]; }

    // denom + app from 32 chunk partials
    float den = 0.f;
#pragma unroll 8
    for (int i = 0; i < 32; ++i) den += ws[WSF_ADEN + i];
    const float invS = 1.0f / den;
    float a0 = 0.f, a1 = 0.f;
#pragma unroll 8
    for (int p = 0; p < 32; ++p) {
        a0 += ws[WSF_APART + p*1024 + l];
        a1 += ws[WSF_APART + p*1024 + 512 + l];
    }
    const int x = xidx[0];
    s_com[0][l] = a0 * invS;
    s_com[1][l] = a1 * invS;
    s_com[2][l] = emb[(size_t)x*512 + l];
    __syncthreads();

    // ---- conv4 (3->32) ----
    float px[3][3];
#pragma unroll
    for (int ic = 0; ic < 3; ++ic) {
        px[ic][0] = (l > 0)   ? s_com[ic][l-1] : 0.f;
        px[ic][1] =             s_com[ic][l];
        px[ic][2] = (l < 511) ? s_com[ic][l+1] : 0.f;
    }
#pragma unroll 4
    for (int oc = 0; oc < 32; ++oc) {
        float a = s_w[B4 + oc];
#pragma unroll
        for (int ic = 0; ic < 3; ++ic)
#pragma unroll
            for (int k = 0; k < 3; ++k)
                a += s_w[W4 + oc*9 + ic*3 + k] * px[ic][k];
        s_y[oc][l] = a;
    }
    __syncthreads();
#pragma unroll
    for (int t = 0; t < 4; ++t) {
        const int oc = wid * 4 + t;
        float s = 0.f, s2 = 0.f;
#pragma unroll
        for (int j = 0; j < 8; ++j) { float v = s_y[oc][lane + j*64]; s += v; s2 += v*v; }
        s = wave_rsum(s); s2 = wave_rsum(s2);
        if (lane == 0) { float m = s/512.f, var = s2/512.f - m*m; s_stat[oc][0] = m; s_stat[oc][1] = rsqrtf(var + 1e-5f); }
    }
    __syncthreads();
#pragma unroll 4
    for (int oc = 0; oc < 32; ++oc)
        s_y[oc][l] = fmaxf((s_y[oc][l] - s_stat[oc][0]) * s_stat[oc][1] * s_w[G4+oc] + s_w[BB4+oc], 0.f);
    __syncthreads();

    // ---- conv5 (32->3) + residual ----
    float y2[3];
#pragma unroll
    for (int oc = 0; oc < 3; ++oc) y2[oc] = s_w[B5 + oc];
#pragma unroll 2
    for (int ic = 0; ic < 32; ++ic) {
        float c0 = (l > 0)   ? s_y[ic][l-1] : 0.f;
        float c1 =             s_y[ic][l];
        float c2 = (l < 511) ? s_y[ic][l+1] : 0.f;
#pragma unroll
        for (int oc = 0; oc < 3; ++oc) {
            const int base = W5 + (oc*32 + ic)*3;
            y2[oc] += s_w[base]*c0 + s_w[base+1]*c1 + s_w[base+2]*c2;
        }
    }
#pragma unroll
    for (int oc = 0; oc < 3; ++oc) y2[oc] += s_com[oc][l];
    __syncthreads();
#pragma unroll
    for (int oc = 0; oc < 3; ++oc) s_y[oc][l] = y2[oc];
    __syncthreads();
    if (wid < 3) {
        const int oc = wid;
        float s = 0.f, s2 = 0.f;
#pragma unroll
        for (int j = 0; j < 8; ++j) { float v = s_y[oc][lane + j*64]; s += v; s2 += v*v; }
        s = wave_rsum(s); s2 = wave_rsum(s2);
        if (lane == 0) { float m = s/512.f, var = s2/512.f - m*m; s_stat[oc][0] = m; s_stat[oc][1] = rsqrtf(var + 1e-5f); }
    }
    __syncthreads();
#pragma unroll
    for (int oc = 0; oc < 3; ++oc)
        s_com[oc][l] = fmaxf((y2[oc] - s_stat[oc][0]) * s_stat[oc][1] * s_w[G5+oc] + s_w[BB5+oc], 0.f);
    __syncthreads();

    // ---- conv6 (3->1) ----
    float a6 = s_w[B6];
#pragma unroll
    for (int ic = 0; ic < 3; ++ic) {
        float c0 = (l > 0)   ? s_com[ic][l-1] : 0.f;
        float c1 =             s_com[ic][l];
        float c2 = (l < 511) ? s_com[ic][l+1] : 0.f;
        a6 += s_w[W6+ic*3]*c0 + s_w[W6+ic*3+1]*c1 + s_w[W6+ic*3+2]*c2;
    }
    s_y[0][l] = a6;
    __syncthreads();
    if (wid == 0) {
        float s = 0.f, s2 = 0.f;
#pragma unroll
        for (int j = 0; j < 8; ++j) { float v = s_y[0][lane + j*64]; s += v; s2 += v*v; }
        s = wave_rsum(s); s2 = wave_rsum(s2);
        if (lane == 0) { float m = s/512.f, var = s2/512.f - m*m; s_stat[0][0] = m; s_stat[0][1] = rsqrtf(var + 1e-5f); }
    }
    __syncthreads();
    ws[WSF_XT + l] = fmaxf((a6 - s_stat[0][0]) * s_stat[0][1] * s_w[G6] + s_w[BB6], 0.f);
}

// =====================================================================
// K4: one GRU layer (R3-proven).  64 blocks x 256; block owns 8 units,
// computes all 6 GEMV rows per unit locally.
// =====================================================================
__global__ __launch_bounds__(256) void k_gru(
    const float* __restrict__ wih, const float* __restrict__ whh,
    const float* __restrict__ bih, const float* __restrict__ bhh,
    const float* __restrict__ hstate,
    const float* __restrict__ xt_in, float* __restrict__ xt_out,
    float* __restrict__ hout, int layer)
{
    wih += (size_t)layer * 1536 * 512;
    whh += (size_t)layer * 1536 * 512;
    bih += layer * 1536;
    bhh += layer * 1536;
    const float* hp = hstate + layer * 512;

    const int tid = threadIdx.x, lane = tid & 63, wid = tid >> 6;
    float xq0[4], xq1[4], hq0[4], hq1[4];
#pragma unroll
    for (int j = 0; j < 4; ++j) {
        xq0[j] = xt_in[lane*4 + j];
        xq1[j] = xt_in[256 + lane*4 + j];
        hq0[j] = hp[lane*4 + j];
        hq1[j] = hp[256 + lane*4 + j];
    }
    __shared__ float s_g[8][6];
    const int i0 = blockIdx.x * 8;
#pragma unroll
    for (int t = 0; t < 2; ++t) {
        const int ii = wid * 2 + t;
        const int i = i0 + ii;
        float a[6] = {0.f, 0.f, 0.f, 0.f, 0.f, 0.f};
#pragma unroll
        for (int g = 0; g < 3; ++g) {
            const float* wr = wih + (size_t)(i + g*512) * 512;
            f32x4 w0 = *(const f32x4*)(wr + lane*4);
            f32x4 w1 = *(const f32x4*)(wr + 256 + lane*4);
#pragma unroll
            for (int j = 0; j < 4; ++j) a[g] += w0[j]*xq0[j] + w1[j]*xq1[j];
        }
#pragma unroll
        for (int g = 0; g < 3; ++g) {
            const float* wr = whh + (size_t)(i + g*512) * 512;
            f32x4 w0 = *(const f32x4*)(wr + lane*4);
            f32x4 w1 = *(const f32x4*)(wr + 256 + lane*4);
#pragma unroll
            for (int j = 0; j < 4; ++j) a[3+g] += w0[j]*hq0[j] + w1[j]*hq1[j];
        }
#pragma unroll
        for (int g = 0; g < 6; ++g) a[g] = wave_rsum(a[g]);
        if (lane == 0) {
#pragma unroll
            for (int g = 0; g < 6; ++g) s_g[ii][g] = a[g];
        }
    }
    __syncthreads();
    if (tid < 8) {
        const int i = i0 + tid;
        float ir = s_g[tid][0] + bih[i];
        float iz = s_g[tid][1] + bih[i + 512];
        float in_ = s_g[tid][2] + bih[i + 1024];
        float hr = s_g[tid][3] + bhh[i];
        float hz = s_g[tid][4] + bhh[i + 512];
        float hn = s_g[tid][5] + bhh[i + 1024];
        float r = sigm(ir + hr);
        float z = sigm(iz + hz);
        float n = tanhf(in_ + r * hn);
        float h = (1.f - z) * n + z * hp[i];
        xt_out[i] = h;
        hout[i] = h;
    }
}

// =====================================================================
// K5: vocab GEMV + per-block online (max, sum-exp).  786 blocks x 256
// =====================================================================
__global__ __launch_bounds__(256) void k_vocab(
    const float* __restrict__ low, const float* __restrict__ lob,
    float* __restrict__ ws)
{
    const int tid = threadIdx.x, lane = tid & 63, wid = tid >> 6;
    float q0[4], q1[4];
#pragma unroll
    for (int j = 0; j < 4; ++j) {
        q0[j] = ws[WSF_XT + 4*512 + lane*4 + j];
        q1[j] = ws[WSF_XT + 4*512 + 256 + lane*4 + j];
    }
    const int row0 = blockIdx.x * 64 + wid * 16;
    float m = -INFINITY, s = 0.0f;
#pragma unroll 4
    for (int r = 0; r < 16; ++r) {
        const int row = row0 + r;
        if (row < NVOCAB) {
            f32x4 w0 = *(const f32x4*)(low + (size_t)row*512 + lane*4);
            f32x4 w1 = *(const f32x4*)(low + (size_t)row*512 + 256 + lane*4);
            float a = 0.f;
#pragma unroll
            for (int j = 0; j < 4; ++j) a += w0[j]*q0[j] + w1[j]*q1[j];
            a = wave_rsum(a);
            if (lane == 0) {
                float v = a + lob[row];
                ws[WSF_LOGV + row] = v;
                if (v > m) { s = s * __expf(m - v) + 1.0f; m = v; }
                else       { s += __expf(v - m); }
            }
        }
    }
    __shared__ float smx[4], ssx[4];
    if (lane == 0) { smx[wid] = m; ssx[wid] = s; }
    __syncthreads();
    if (tid == 0) {
        float M = -INFINITY, S = 0.0f;
#pragma unroll
        for (int w = 0; w < 4; ++w) {
            float mb = smx[w], sb = ssx[w];
            if (sb > 0.0f) {
                if (mb > M) { S = S * __expf(M - mb) + sb; M = mb; }
                else        { S += sb * __expf(mb - M); }
            }
        }
        ws[WSF_PM + blockIdx.x] = M;
        ws[WSF_PS + blockIdx.x] = S;
    }
}

// =====================================================================
// K6: redundant deterministic LSE + write log-probs.  197 blocks x 256
// =====================================================================
__global__ __launch_bounds__(256) void k_outlse(
    const float* __restrict__ ws, float* __restrict__ out)
{
    __shared__ float smx[256], ssx[256];
    const int tid = threadIdx.x;
    float M = -INFINITY, S = 0.0f;
    for (int i = tid; i < NBLK_V; i += 256) {
        float mb = ws[WSF_PM + i], sb = ws[WSF_PS + i];
        if (mb > M) { S = S * __expf(M - mb) + sb; M = mb; }
        else        { S += sb * __expf(mb - M); }
    }
    smx[tid] = M; ssx[tid] = S;
    __syncthreads();
    for (int st = 128; st > 0; st >>= 1) {
        if (tid < st) {
            float mb = smx[tid + st], sb = ssx[tid + st];
            if (sb > 0.0f) {
                if (mb > smx[tid]) { ssx[tid] = ssx[tid] * __expf(smx[tid] - mb) + sb; smx[tid] = mb; }
                else               { ssx[tid] += sb * __expf(mb - smx[tid]); }
            }
        }
        __syncthreads();
    }
    const float lse = smx[0] + logf(ssx[0]);
    const int i = blockIdx.x * 256 + tid;
    if (i < NVOCAB) out[i] = ws[WSF_LOGV + i] - lse;
}

// =====================================================================
extern "C" void kernel_launch(void* const* d_in, const int* in_sizes, int n_in,
                              void* d_out, int out_size, void* d_ws, size_t ws_size,
                              hipStream_t stream)
{
    (void)in_sizes; (void)n_in; (void)out_size; (void)ws_size;
    const float* emb     = (const float*)d_in[0];
    const float* conv1_w = (const float*)d_in[1];  const float* conv1_b = (const float*)d_in[2];
    const float* conv2_w = (const float*)d_in[3];  const float* conv2_b = (const float*)d_in[4];
    const float* conv3_w = (const float*)d_in[5];  const float* conv3_b = (const float*)d_in[6];
    const float* conv4_w = (const float*)d_in[7];  const float* conv4_b = (const float*)d_in[8];
    const float* conv5_w = (const float*)d_in[9];  const float* conv5_b = (const float*)d_in[10];
    const float* conv6_w = (const float*)d_in[11]; const float* conv6_b = (const float*)d_in[12];
    const float* bn1_g = (const float*)d_in[13];   const float* bn1_b = (const float*)d_in[14];
    const float* bn2_g = (const float*)d_in[15];   const float* bn2_b = (const float*)d_in[16];
    const float* bn3_g = (const float*)d_in[17];   const float* bn3_b = (const float*)d_in[18];
    const float* bn4_g = (const float*)d_in[19];   const float* bn4_b = (const float*)d_in[20];
    const float* bn5_g = (const float*)d_in[21];   const float* bn5_b = (const float*)d_in[22];
    const float* bn6_g = (const float*)d_in[23];   const float* bn6_b = (const float*)d_in[24];
    const float* att_w = (const float*)d_in[25];   const float* att_b = (const float*)d_in[26];
    const float* gru_wih = (const float*)d_in[27]; const float* gru_whh = (const float*)d_in[28];
    const float* gru_bih = (const float*)d_in[29]; const float* gru_bhh = (const float*)d_in[30];
    const float* lo_w = (const float*)d_in[31];    const float* lo_b = (const float*)d_in[32];
    const float* h_state = (const float*)d_in[33];
    const float* enc = (const float*)d_in[34];
    const int* x = (const int*)d_in[35];

    float* ws = (float*)d_ws;
    float* out = (float*)d_out;

    k_pre<<<1, 512, 0, stream>>>(emb, x, h_state,
        conv1_w, conv1_b, conv2_w, conv2_b, conv3_w, conv3_b,
        bn1_g, bn1_b, bn2_g, bn2_b, bn3_g, bn3_b, ws);
    k_att<<<32, 256, 0, stream>>>(att_w, att_b, enc, ws);
    k_post<<<1, 512, 0, stream>>>(emb, x,
        conv4_w, conv4_b, conv5_w, conv5_b, conv6_w, conv6_b,
        bn4_g, bn4_b, bn5_g, bn5_b, bn6_g, bn6_b, ws);
    for (int l = 0; l < 4; ++l) {
        k_gru<<<64, 256, 0, stream>>>(gru_wih, gru_whh, gru_bih, gru_bhh, h_state,
            ws + WSF_XT + l * 512, ws + WSF_XT + (l + 1) * 512,
            out + NVOCAB + l * 512, l);
    }
    k_vocab<<<NBLK_V, 256, 0, stream>>>(lo_w, lo_b, ws);
    k_outlse<<<197, 256, 0, stream>>>(ws, out);
}